// Round 3
// baseline (350.488 us; speedup 1.0000x reference)
//
#include <hip/hip_runtime.h>
#include <hip/hip_fp16.h>

#define SLOTS 64
#define DEGSTRIDE 16  // pad deg counters to 64B: kills same-line atomic serialization

typedef _Float16 half8 __attribute__((ext_vector_type(8)));
typedef float f32x4 __attribute__((ext_vector_type(4)));

// ---------- padded CSR build, XCD-range-filtered, NODE-MAJOR, 4-edge ILP ----------
// grid = 8 ranges x `chunks` chunks over 4-edge groups. blockIdx&7 ~ XCD id
// (round-robin dispatch) -> each range's atomics+writes stay in one XCD's L2.
// Each thread owns an aligned int4 of dst -> 4 INDEPENDENT atomic->store chains
// in flight (the old per-edge serial chain was the latency bottleneck).
__global__ __launch_bounds__(256) void fill_pad(const int* __restrict__ src,
                                                const int* __restrict__ dst, int E, int N,
                                                int* __restrict__ degp,
                                                int* __restrict__ colpad, int chunks) {
  int range = blockIdx.x & 7;
  int chunk = blockIdx.x >> 3;
  int per = (N + 7) >> 3;
  int lo = range * per, hi = min(N, lo + per);
  int W4 = (E + 3) >> 2;  // 4-edge work items; edge base 4*w is 16B-aligned
  int w0 = (int)((long long)chunk * W4 / chunks);
  int w1 = (int)((long long)(chunk + 1) * W4 / chunks);
  for (int w = w0 + (int)threadIdx.x; w < w1; w += 256) {
    int e = w << 2;
    int4 d4, s4;
    if (e + 3 < E) {
      d4 = *(const int4*)&dst[e];
      bool m0 = (d4.x >= lo) & (d4.x < hi);
      bool m1 = (d4.y >= lo) & (d4.y < hi);
      bool m2 = (d4.z >= lo) & (d4.z < hi);
      bool m3 = (d4.w >= lo) & (d4.w < hi);
      if (!(m0 | m1 | m2 | m3)) continue;
      s4 = *(const int4*)&src[e];  // one dwordx4, only when needed (41% of groups)
    } else {  // tail group
      d4 = make_int4(-1, -1, -1, -1);
      s4 = make_int4(0, 0, 0, 0);
      if (e + 0 < E) { d4.x = dst[e + 0]; s4.x = src[e + 0]; }
      if (e + 1 < E) { d4.y = dst[e + 1]; s4.y = src[e + 1]; }
      if (e + 2 < E) { d4.z = dst[e + 2]; s4.z = src[e + 2]; }
      if (e + 3 < E) { d4.w = dst[e + 3]; s4.w = src[e + 3]; }
    }
    if (d4.x >= lo && d4.x < hi) {
      int p = atomicAdd(&degp[(size_t)d4.x * DEGSTRIDE], 1);
      if (p < SLOTS) colpad[(size_t)d4.x * SLOTS + p] = s4.x;
    }
    if (d4.y >= lo && d4.y < hi) {
      int p = atomicAdd(&degp[(size_t)d4.y * DEGSTRIDE], 1);
      if (p < SLOTS) colpad[(size_t)d4.y * SLOTS + p] = s4.y;
    }
    if (d4.z >= lo && d4.z < hi) {
      int p = atomicAdd(&degp[(size_t)d4.z * DEGSTRIDE], 1);
      if (p < SLOTS) colpad[(size_t)d4.z * SLOTS + p] = s4.z;
    }
    if (d4.w >= lo && d4.w < hi) {
      int p = atomicAdd(&degp[(size_t)d4.w * DEGSTRIDE], 1);
      if (p < SLOTS) colpad[(size_t)d4.w * SLOTS + p] = s4.w;
    }
  }
}

// compact padded counters + compute dinv
__global__ __launch_bounds__(256) void calc_dinv(const int* __restrict__ degp,
                                                 float* __restrict__ dinv,
                                                 int* __restrict__ degc, int N) {
  int i = blockIdx.x * 256 + threadIdx.x;
  if (i < N) {
    int d = degp[(size_t)i * DEGSTRIDE];
    dinv[i] = rsqrtf((float)(d + 1));  // +1 self loop
    degc[i] = min(d, SLOTS);
  }
}

// ---------- MFMA GEMM: out[i][c] = half(dinv[i] * sum_k in[i][k]*W[k][c]) ----------
// 64 rows x 64 cols per block-tile, 4 waves (16 rows each, all 64 cols via 4 acc).
// A-fragments direct global->reg, DOUBLE-BUFFERED across the tile loop so next
// tile's loads overlap this tile's MFMA+store. W^T in LDS once -> no loop barriers.
//   A frag: lane l holds A[l&15][kk*32 + (l>>4)*8 + j], j=0..7
//   B frag: lane l holds B[kk*32 + (l>>4)*8 + j][l&15]  (from Wt[col][k], contiguous)
//   D frag: col = l&15, row = (l>>4)*4 + reg   (harness-verified)
template <int K, typename Tin>
__global__ __launch_bounds__(256) void gemm_mfma(const Tin* __restrict__ in,
                                                 const float* __restrict__ W,
                                                 const float* __restrict__ dinv,
                                                 __half* __restrict__ out,
                                                 int N, int tiles) {
  constexpr int LDK = K + 8;
  __shared__ __align__(16) _Float16 Wt[64][LDK];
  int t = threadIdx.x;
  for (int j = t; j < K * 64; j += 256) {  // coalesced global read of W [K][64]
    int k = j >> 6, c = j & 63;
    Wt[c][k] = (_Float16)W[j];
  }
  __syncthreads();
  int wave = t >> 6, lane = t & 63;
  int arow = lane & 15, kgrp = lane >> 4;
  constexpr int KK = K / 32;

  auto load_af = [&](int tile, half8* af) {
    int row = tile * 64 + wave * 16 + arow;
    if (row < N) {
#pragma unroll
      for (int kk = 0; kk < KK; ++kk) {
        if constexpr (sizeof(Tin) == 4) {
          const float4* p = (const float4*)&in[(size_t)row * K + kk * 32 + kgrp * 8];
          float4 v0 = p[0], v1 = p[1];
          half8 h;
          h[0] = (_Float16)v0.x; h[1] = (_Float16)v0.y;
          h[2] = (_Float16)v0.z; h[3] = (_Float16)v0.w;
          h[4] = (_Float16)v1.x; h[5] = (_Float16)v1.y;
          h[6] = (_Float16)v1.z; h[7] = (_Float16)v1.w;
          af[kk] = h;
        } else {
          af[kk] = *(const half8*)&in[(size_t)row * K + kk * 32 + kgrp * 8];
        }
      }
    } else {
#pragma unroll
      for (int kk = 0; kk < KK; ++kk) af[kk] = (half8)((_Float16)0.f);
    }
  };

  half8 afA[KK], afB[KK];
  int tile = blockIdx.x;
  if (tile < tiles) load_af(tile, afA);
  for (; tile < tiles; tile += gridDim.x) {
    int nxt = tile + gridDim.x;
    if (nxt < tiles) load_af(nxt, afB);   // overlaps MFMA+store below
    f32x4 acc[4];
#pragma unroll
    for (int ct = 0; ct < 4; ++ct) acc[ct] = (f32x4)(0.f);
#pragma unroll
    for (int kk = 0; kk < KK; ++kk) {
#pragma unroll
      for (int ct = 0; ct < 4; ++ct) {
        half8 b = *(const half8*)&Wt[ct * 16 + arow][kk * 32 + kgrp * 8];
        acc[ct] = __builtin_amdgcn_mfma_f32_16x16x32_f16(afA[kk], b, acc[ct], 0, 0, 0);
      }
    }
    int rbase = tile * 64 + wave * 16 + kgrp * 4;
#pragma unroll
    for (int r = 0; r < 4; ++r) {
      int rr = rbase + r;
      if (rr < N) {
        float s = dinv[rr];
#pragma unroll
        for (int ct = 0; ct < 4; ++ct)
          out[(size_t)rr * 64 + ct * 16 + arow] = __float2half(acc[ct][r] * s);
      }
    }
#pragma unroll
    for (int kk = 0; kk < KK; ++kk) afA[kk] = afB[kk];
  }
}

// ---------- aggregation: h[d] = dinv[d]*(g[d] + sum_nb g[s]) + b ----------
// one wave per contiguous node chunk; lane = feature column. colpad node-major:
// neighbor list read is ONE coalesced load per node. 16 gathers in flight
// (deg mean ~16, L3 gather latency ~600cy -> depth is the lever), next node's
// deg/nb prefetched to break the inter-node chain.
__global__ __launch_bounds__(256) void aggregate(const __half* __restrict__ g,
                                                 const int* __restrict__ degc,
                                                 const int* __restrict__ colpad,
                                                 const float* __restrict__ dinv,
                                                 const float* __restrict__ bias,
                                                 const int* __restrict__ batch,
                                                 __half* __restrict__ out,
                                                 float* __restrict__ poolsum,
                                                 float* __restrict__ poolcnt,
                                                 int N, int mode) {
  int lane = threadIdx.x & 63;
  int wave = blockIdx.x * 4 + (threadIdx.x >> 6);
  int nwaves = gridDim.x * 4;
  int per = (N + nwaves - 1) / nwaves;
  int n0 = wave * per, n1 = min(N, n0 + per);
  if (n0 >= n1) return;
  float b = bias[lane];
  int cur = mode ? batch[n0] : 0;
  float pacc = 0.f, pcnt = 0.f;
  int deg = degc[n0];
  int nb = colpad[(size_t)n0 * SLOTS + lane];
  for (int node = n0; node < n1; ++node) {
    int nxt = (node + 1 < n1) ? node + 1 : node;
    int dn = degc[nxt];                              // prefetch next node
    int nbn = colpad[(size_t)nxt * SLOTS + lane];
    float a0 = __half2float(g[(size_t)node * 64 + lane]);  // self (dinv-prescaled)
    float a1 = 0.f, a2 = 0.f, a3 = 0.f;
    float a4 = 0.f, a5 = 0.f, a6 = 0.f, a7 = 0.f;
    float a8 = 0.f, a9 = 0.f, aA = 0.f, aB = 0.f;
    float aC = 0.f, aD = 0.f, aE = 0.f, aF = 0.f;
    int j = 0;
    for (; j + 15 < deg; j += 16) {  // 16 independent gathers in flight
      int s0 = __shfl(nb, j, 64);
      int s1 = __shfl(nb, j + 1, 64);
      int s2 = __shfl(nb, j + 2, 64);
      int s3 = __shfl(nb, j + 3, 64);
      int s4 = __shfl(nb, j + 4, 64);
      int s5 = __shfl(nb, j + 5, 64);
      int s6 = __shfl(nb, j + 6, 64);
      int s7 = __shfl(nb, j + 7, 64);
      int s8 = __shfl(nb, j + 8, 64);
      int s9 = __shfl(nb, j + 9, 64);
      int sA = __shfl(nb, j + 10, 64);
      int sB = __shfl(nb, j + 11, 64);
      int sC = __shfl(nb, j + 12, 64);
      int sD = __shfl(nb, j + 13, 64);
      int sE = __shfl(nb, j + 14, 64);
      int sF = __shfl(nb, j + 15, 64);
      a0 += __half2float(g[(size_t)s0 * 64 + lane]);
      a1 += __half2float(g[(size_t)s1 * 64 + lane]);
      a2 += __half2float(g[(size_t)s2 * 64 + lane]);
      a3 += __half2float(g[(size_t)s3 * 64 + lane]);
      a4 += __half2float(g[(size_t)s4 * 64 + lane]);
      a5 += __half2float(g[(size_t)s5 * 64 + lane]);
      a6 += __half2float(g[(size_t)s6 * 64 + lane]);
      a7 += __half2float(g[(size_t)s7 * 64 + lane]);
      a8 += __half2float(g[(size_t)s8 * 64 + lane]);
      a9 += __half2float(g[(size_t)s9 * 64 + lane]);
      aA += __half2float(g[(size_t)sA * 64 + lane]);
      aB += __half2float(g[(size_t)sB * 64 + lane]);
      aC += __half2float(g[(size_t)sC * 64 + lane]);
      aD += __half2float(g[(size_t)sD * 64 + lane]);
      aE += __half2float(g[(size_t)sE * 64 + lane]);
      aF += __half2float(g[(size_t)sF * 64 + lane]);
    }
    for (; j + 7 < deg; j += 8) {
      int s0 = __shfl(nb, j, 64);
      int s1 = __shfl(nb, j + 1, 64);
      int s2 = __shfl(nb, j + 2, 64);
      int s3 = __shfl(nb, j + 3, 64);
      int s4 = __shfl(nb, j + 4, 64);
      int s5 = __shfl(nb, j + 5, 64);
      int s6 = __shfl(nb, j + 6, 64);
      int s7 = __shfl(nb, j + 7, 64);
      a0 += __half2float(g[(size_t)s0 * 64 + lane]);
      a1 += __half2float(g[(size_t)s1 * 64 + lane]);
      a2 += __half2float(g[(size_t)s2 * 64 + lane]);
      a3 += __half2float(g[(size_t)s3 * 64 + lane]);
      a4 += __half2float(g[(size_t)s4 * 64 + lane]);
      a5 += __half2float(g[(size_t)s5 * 64 + lane]);
      a6 += __half2float(g[(size_t)s6 * 64 + lane]);
      a7 += __half2float(g[(size_t)s7 * 64 + lane]);
    }
    for (; j + 3 < deg; j += 4) {
      int s0 = __shfl(nb, j, 64);
      int s1 = __shfl(nb, j + 1, 64);
      int s2 = __shfl(nb, j + 2, 64);
      int s3 = __shfl(nb, j + 3, 64);
      a0 += __half2float(g[(size_t)s0 * 64 + lane]);
      a1 += __half2float(g[(size_t)s1 * 64 + lane]);
      a2 += __half2float(g[(size_t)s2 * 64 + lane]);
      a3 += __half2float(g[(size_t)s3 * 64 + lane]);
    }
    for (; j < deg; ++j) a0 += __half2float(g[(size_t)__shfl(nb, j, 64) * 64 + lane]);
    float r = dinv[node] * ((((a0 + a1) + (a2 + a3)) + ((a4 + a5) + (a6 + a7))) +
                            (((a8 + a9) + (aA + aB)) + ((aC + aD) + (aE + aF)))) + b;
    deg = dn;
    nb = nbn;
    if (mode == 0) {
      out[(size_t)node * 64 + lane] = __float2half(fmaxf(r, 0.f));
    } else {
      int bg = batch[node];
      if (bg != cur) {
        atomicAdd(&poolsum[cur * 64 + lane], pacc);
        if (lane == 0) atomicAdd(&poolcnt[cur], pcnt);
        pacc = 0.f; pcnt = 0.f; cur = bg;
      }
      pacc += r; pcnt += 1.f;
    }
  }
  if (mode) {
    atomicAdd(&poolsum[cur * 64 + lane], pacc);
    if (lane == 0) atomicAdd(&poolcnt[cur], pcnt);
  }
}

__global__ __launch_bounds__(256) void finalize(const float* __restrict__ poolsum,
                                                const float* __restrict__ poolcnt,
                                                float* __restrict__ out, int Gn) {
  int i = blockIdx.x * 256 + threadIdx.x;
  if (i < Gn * 64) {
    float c = poolcnt[i >> 6];
    out[i] = poolsum[i] / fmaxf(c, 1.f);
  }
}

extern "C" void kernel_launch(void* const* d_in, const int* in_sizes, int n_in,
                              void* d_out, int out_size, void* d_ws, size_t ws_size,
                              hipStream_t stream) {
  const float* x   = (const float*)d_in[0];
  const int* ei    = (const int*)d_in[1];
  const int* batch = (const int*)d_in[2];
  const float* W1  = (const float*)d_in[3];
  const float* b1  = (const float*)d_in[4];
  const float* W2  = (const float*)d_in[5];
  const float* b2  = (const float*)d_in[6];
  float* out = (float*)d_out;

  int N  = in_sizes[2];
  int E  = in_sizes[1] / 2;
  int Gn = out_size / 64;

  char* ws = (char*)d_ws;
  size_t off = 0;
  auto alloc = [&](size_t bytes) -> void* {
    void* p = ws + off;
    off = (off + bytes + 255) & ~(size_t)255;
    return p;
  };
  float* poolsum = (float*)alloc(4ull * Gn * 64);
  float* poolcnt = (float*)alloc(4ull * Gn);
  size_t zero_bytes = off;  // zero-init region (pool accumulators)
  int* colpad    = (int*)alloc(4ull * (size_t)N * SLOTS);
  float* dinv    = (float*)alloc(4ull * N);
  int* degc      = (int*)alloc(4ull * N);
  __half* gbuf   = (__half*)alloc(2ull * (size_t)N * 64);
  __half* ybuf   = (__half*)alloc(2ull * (size_t)N * 64);
  // padded deg counters alias gbuf: needed only before gemm1 writes gbuf
  int* degp = (int*)gbuf;  // 4*DEGSTRIDE*N = 6.4MB <= 12.8MB gbuf
  (void)ws_size; (void)n_in;

  hipMemsetAsync(poolsum, 0, zero_bytes, stream);
  hipMemsetAsync(degp, 0, 4ull * (size_t)N * DEGSTRIDE, stream);

  const int* srcv = ei;
  const int* dstv = ei + E;
  int tiles64 = (N + 63) / 64;

  fill_pad<<<8 * 256, 256, 0, stream>>>(srcv, dstv, E, N, degp, colpad, 256);
  calc_dinv<<<(N + 255) / 256, 256, 0, stream>>>(degp, dinv, degc, N);

  // layer 1
  gemm_mfma<128, float><<<512, 256, 0, stream>>>(x, W1, dinv, gbuf, N, tiles64);
  aggregate<<<2048, 256, 0, stream>>>(gbuf, degc, colpad, dinv, b1, batch, ybuf,
                                      nullptr, nullptr, N, 0);
  // layer 2 (+fused mean-pool partials)
  gemm_mfma<64, __half><<<512, 256, 0, stream>>>(ybuf, W2, dinv, gbuf, N, tiles64);
  aggregate<<<2048, 256, 0, stream>>>(gbuf, degc, colpad, dinv, b2, batch, nullptr,
                                      poolsum, poolcnt, N, 1);
  finalize<<<(Gn * 64 + 255) / 256, 256, 0, stream>>>(poolsum, poolcnt, out, Gn);
}

// Round 4
// 306.970 us; speedup vs baseline: 1.1418x; 1.1418x over previous
//
#include <hip/hip_runtime.h>
#include <hip/hip_fp16.h>

#define SLOTS 64
#define DEGSTRIDE 16  // pad deg counters to 64B: kills same-line atomic serialization

typedef _Float16 half8 __attribute__((ext_vector_type(8)));
typedef float f32x4 __attribute__((ext_vector_type(4)));

// ---------- padded CSR build, XCD-range-filtered, NODE-MAJOR ----------
// grid = 8 ranges x `chunks` edge-chunks. Block b: dst-range (b&7), edge chunk (b>>3).
// blockIdx&7 ~ XCD id (round-robin dispatch) -> each range's atomics+writes stay in
// one XCD's L2. colpad[d*64+p]: same-d slots share a cache line -> L2 write merge.
// (r2-measured form: 75 us. r3's 4-edge ILP variant was not separable; reverted.)
__global__ __launch_bounds__(256) void fill_pad(const int* __restrict__ src,
                                                const int* __restrict__ dst, int E, int N,
                                                int* __restrict__ degp,
                                                int* __restrict__ colpad, int chunks) {
  int range = blockIdx.x & 7;
  int chunk = blockIdx.x >> 3;
  int per = (N + 7) >> 3;
  int lo = range * per, hi = min(N, lo + per);
  int e0 = (int)((long long)chunk * E / chunks);
  int e1 = (int)((long long)(chunk + 1) * E / chunks);
  for (int e = e0 + (int)threadIdx.x; e < e1; e += 256) {
    int d = dst[e];
    if (d >= lo && d < hi) {
      int p = atomicAdd(&degp[(size_t)d * DEGSTRIDE], 1);
      if (p < SLOTS) colpad[(size_t)d * SLOTS + p] = src[e];
    }
  }
}

// compact padded counters + compute dinv
__global__ __launch_bounds__(256) void calc_dinv(const int* __restrict__ degp,
                                                 float* __restrict__ dinv,
                                                 int* __restrict__ degc, int N) {
  int i = blockIdx.x * 256 + threadIdx.x;
  if (i < N) {
    int d = degp[(size_t)i * DEGSTRIDE];
    dinv[i] = rsqrtf((float)(d + 1));  // +1 self loop
    degc[i] = min(d, SLOTS);
  }
}

// ---------- MFMA GEMM: out[i][c] = half(dinv[i] * sum_k in[i][k]*W[k][c]) ----------
// 64 rows x 64 cols per block, 4 waves (16 rows each, all 64 cols via 4 acc).
// KEY CHANGE vs r2: A-fragment + dinv loads are issued BEFORE the W-stage, so the
// A-load HBM latency (~900cy) hides under the W-stage latency instead of being
// serialized after the barrier. Per-block critical path ~2100cy -> ~1200cy.
//   A frag: lane l holds A[l&15][kk*32 + (l>>4)*8 + j], j=0..7
//   B frag: lane l holds B[kk*32 + (l>>4)*8 + j][l&15]  (from Wt[col][k], contiguous)
//   D frag: col = l&15, row = (l>>4)*4 + reg   (harness-verified)
template <int K, typename Tin>
__global__ __launch_bounds__(256) void gemm_mfma(const Tin* __restrict__ in,
                                                 const float* __restrict__ W,
                                                 const float* __restrict__ dinv,
                                                 __half* __restrict__ out,
                                                 int N) {
  constexpr int LDK = K + 8;
  __shared__ __align__(16) _Float16 Wt[64][LDK];
  int t = threadIdx.x;
  int wave = t >> 6, lane = t & 63;
  int arow = lane & 15, kgrp = lane >> 4;
  constexpr int KK = K / 32;
  int row0 = blockIdx.x * 64;
  int row = row0 + wave * 16 + arow;

  // ---- (1) issue A loads first (independent of W) ----
  half8 af[KK];
  if (row < N) {
#pragma unroll
    for (int kk = 0; kk < KK; ++kk) {
      if constexpr (sizeof(Tin) == 4) {
        const float4* p = (const float4*)&in[(size_t)row * K + kk * 32 + kgrp * 8];
        float4 v0 = p[0], v1 = p[1];
        half8 h;
        h[0] = (_Float16)v0.x; h[1] = (_Float16)v0.y;
        h[2] = (_Float16)v0.z; h[3] = (_Float16)v0.w;
        h[4] = (_Float16)v1.x; h[5] = (_Float16)v1.y;
        h[6] = (_Float16)v1.z; h[7] = (_Float16)v1.w;
        af[kk] = h;
      } else {
        af[kk] = *(const half8*)&in[(size_t)row * K + kk * 32 + kgrp * 8];
      }
    }
  } else {
#pragma unroll
    for (int kk = 0; kk < KK; ++kk) af[kk] = (half8)((_Float16)0.f);
  }
  // dinv for this lane's 4 output rows (also independent of W)
  int rbase = row0 + wave * 16 + kgrp * 4;
  float dv[4];
#pragma unroll
  for (int r = 0; r < 4; ++r) dv[r] = (rbase + r < N) ? dinv[rbase + r] : 0.f;

  // ---- (2) stage W^T to LDS (latency overlaps the A loads above) ----
  for (int j = t; j < K * 64; j += 256) {  // coalesced global read of W [K][64]
    int k = j >> 6, c = j & 63;
    Wt[c][k] = (_Float16)W[j];
  }
  __syncthreads();

  // ---- (3) MFMA ----
  f32x4 acc[4];
#pragma unroll
  for (int ct = 0; ct < 4; ++ct) acc[ct] = (f32x4)(0.f);
#pragma unroll
  for (int kk = 0; kk < KK; ++kk) {
#pragma unroll
    for (int ct = 0; ct < 4; ++ct) {
      half8 b = *(const half8*)&Wt[ct * 16 + arow][kk * 32 + kgrp * 8];
      acc[ct] = __builtin_amdgcn_mfma_f32_16x16x32_f16(af[kk], b, acc[ct], 0, 0, 0);
    }
  }

  // ---- (4) epilogue: scale by dinv, store half ----
#pragma unroll
  for (int r = 0; r < 4; ++r) {
    int rr = rbase + r;
    if (rr < N) {
#pragma unroll
      for (int ct = 0; ct < 4; ++ct)
        out[(size_t)rr * 64 + ct * 16 + arow] = __float2half(acc[ct][r] * dv[r]);
    }
  }
}

// ---------- aggregation: h[d] = dinv[d]*(g[d] + sum_nb g[s]) + b ----------
// r2-measured form (72.5 us): one wave per contiguous node chunk; lane = feature
// column; colpad node-major -> ONE coalesced neighbor-list load per node; 8 gathers
// in flight; next node's deg/nb prefetched. (r3's 16-deep batch regressed 25%.)
__global__ __launch_bounds__(256) void aggregate(const __half* __restrict__ g,
                                                 const int* __restrict__ degc,
                                                 const int* __restrict__ colpad,
                                                 const float* __restrict__ dinv,
                                                 const float* __restrict__ bias,
                                                 const int* __restrict__ batch,
                                                 __half* __restrict__ out,
                                                 float* __restrict__ poolsum,
                                                 float* __restrict__ poolcnt,
                                                 int N, int mode) {
  int lane = threadIdx.x & 63;
  int wave = blockIdx.x * 4 + (threadIdx.x >> 6);
  int nwaves = gridDim.x * 4;
  int per = (N + nwaves - 1) / nwaves;
  int n0 = wave * per, n1 = min(N, n0 + per);
  if (n0 >= n1) return;
  float b = bias[lane];
  int cur = mode ? batch[n0] : 0;
  float pacc = 0.f, pcnt = 0.f;
  int deg = degc[n0];
  int nb = colpad[(size_t)n0 * SLOTS + lane];
  for (int node = n0; node < n1; ++node) {
    int nxt = (node + 1 < n1) ? node + 1 : node;
    int dn = degc[nxt];                              // prefetch next node
    int nbn = colpad[(size_t)nxt * SLOTS + lane];
    float a0 = __half2float(g[(size_t)node * 64 + lane]);  // self (dinv-prescaled)
    float a1 = 0.f, a2 = 0.f, a3 = 0.f;
    float a4 = 0.f, a5 = 0.f, a6 = 0.f, a7 = 0.f;
    int j = 0;
    for (; j + 7 < deg; j += 8) {  // 8 independent gathers in flight
      int s0 = __shfl(nb, j, 64);
      int s1 = __shfl(nb, j + 1, 64);
      int s2 = __shfl(nb, j + 2, 64);
      int s3 = __shfl(nb, j + 3, 64);
      int s4 = __shfl(nb, j + 4, 64);
      int s5 = __shfl(nb, j + 5, 64);
      int s6 = __shfl(nb, j + 6, 64);
      int s7 = __shfl(nb, j + 7, 64);
      a0 += __half2float(g[(size_t)s0 * 64 + lane]);
      a1 += __half2float(g[(size_t)s1 * 64 + lane]);
      a2 += __half2float(g[(size_t)s2 * 64 + lane]);
      a3 += __half2float(g[(size_t)s3 * 64 + lane]);
      a4 += __half2float(g[(size_t)s4 * 64 + lane]);
      a5 += __half2float(g[(size_t)s5 * 64 + lane]);
      a6 += __half2float(g[(size_t)s6 * 64 + lane]);
      a7 += __half2float(g[(size_t)s7 * 64 + lane]);
    }
    for (; j + 3 < deg; j += 4) {
      int s0 = __shfl(nb, j, 64);
      int s1 = __shfl(nb, j + 1, 64);
      int s2 = __shfl(nb, j + 2, 64);
      int s3 = __shfl(nb, j + 3, 64);
      a0 += __half2float(g[(size_t)s0 * 64 + lane]);
      a1 += __half2float(g[(size_t)s1 * 64 + lane]);
      a2 += __half2float(g[(size_t)s2 * 64 + lane]);
      a3 += __half2float(g[(size_t)s3 * 64 + lane]);
    }
    for (; j < deg; ++j) a0 += __half2float(g[(size_t)__shfl(nb, j, 64) * 64 + lane]);
    float r = dinv[node] * (((a0 + a1) + (a2 + a3)) + ((a4 + a5) + (a6 + a7))) + b;
    deg = dn;
    nb = nbn;
    if (mode == 0) {
      out[(size_t)node * 64 + lane] = __float2half(fmaxf(r, 0.f));
    } else {
      int bg = batch[node];
      if (bg != cur) {
        atomicAdd(&poolsum[cur * 64 + lane], pacc);
        if (lane == 0) atomicAdd(&poolcnt[cur], pcnt);
        pacc = 0.f; pcnt = 0.f; cur = bg;
      }
      pacc += r; pcnt += 1.f;
    }
  }
  if (mode) {
    atomicAdd(&poolsum[cur * 64 + lane], pacc);
    if (lane == 0) atomicAdd(&poolcnt[cur], pcnt);
  }
}

__global__ __launch_bounds__(256) void finalize(const float* __restrict__ poolsum,
                                                const float* __restrict__ poolcnt,
                                                float* __restrict__ out, int Gn) {
  int i = blockIdx.x * 256 + threadIdx.x;
  if (i < Gn * 64) {
    float c = poolcnt[i >> 6];
    out[i] = poolsum[i] / fmaxf(c, 1.f);
  }
}

extern "C" void kernel_launch(void* const* d_in, const int* in_sizes, int n_in,
                              void* d_out, int out_size, void* d_ws, size_t ws_size,
                              hipStream_t stream) {
  const float* x   = (const float*)d_in[0];
  const int* ei    = (const int*)d_in[1];
  const int* batch = (const int*)d_in[2];
  const float* W1  = (const float*)d_in[3];
  const float* b1  = (const float*)d_in[4];
  const float* W2  = (const float*)d_in[5];
  const float* b2  = (const float*)d_in[6];
  float* out = (float*)d_out;

  int N  = in_sizes[2];
  int E  = in_sizes[1] / 2;
  int Gn = out_size / 64;

  char* ws = (char*)d_ws;
  size_t off = 0;
  auto alloc = [&](size_t bytes) -> void* {
    void* p = ws + off;
    off = (off + bytes + 255) & ~(size_t)255;
    return p;
  };
  float* poolsum = (float*)alloc(4ull * Gn * 64);
  float* poolcnt = (float*)alloc(4ull * Gn);
  size_t zero_bytes = off;  // zero-init region (pool accumulators)
  int* colpad    = (int*)alloc(4ull * (size_t)N * SLOTS);
  float* dinv    = (float*)alloc(4ull * N);
  int* degc      = (int*)alloc(4ull * N);
  __half* gbuf   = (__half*)alloc(2ull * (size_t)N * 64);
  __half* ybuf   = (__half*)alloc(2ull * (size_t)N * 64);
  // padded deg counters alias gbuf: needed only before gemm1 writes gbuf
  int* degp = (int*)gbuf;  // 4*DEGSTRIDE*N = 6.4MB <= 12.8MB gbuf
  (void)ws_size; (void)n_in;

  hipMemsetAsync(poolsum, 0, zero_bytes, stream);
  hipMemsetAsync(degp, 0, 4ull * (size_t)N * DEGSTRIDE, stream);

  const int* srcv = ei;
  const int* dstv = ei + E;
  int tiles64 = (N + 63) / 64;

  fill_pad<<<8 * 256, 256, 0, stream>>>(srcv, dstv, E, N, degp, colpad, 256);
  calc_dinv<<<(N + 255) / 256, 256, 0, stream>>>(degp, dinv, degc, N);

  // layer 1
  gemm_mfma<128, float><<<tiles64, 256, 0, stream>>>(x, W1, dinv, gbuf, N);
  aggregate<<<2048, 256, 0, stream>>>(gbuf, degc, colpad, dinv, b1, batch, ybuf,
                                      nullptr, nullptr, N, 0);
  // layer 2 (+fused mean-pool partials)
  gemm_mfma<64, __half><<<tiles64, 256, 0, stream>>>(ybuf, W2, dinv, gbuf, N);
  aggregate<<<2048, 256, 0, stream>>>(gbuf, degc, colpad, dinv, b2, batch, nullptr,
                                      poolsum, poolcnt, N, 1);
  finalize<<<(Gn * 64 + 255) / 256, 256, 0, stream>>>(poolsum, poolcnt, out, Gn);
}